// Round 23
// baseline (424.887 us; speedup 1.0000x reference)
//
#include <hip/hip_runtime.h>
#include <math.h>

typedef __attribute__((ext_vector_type(8))) short short8;
typedef __attribute__((ext_vector_type(16))) float f32x16;

#define NCB 4
#define NE 1024
#define DIM 64
#define HW 16384
#define NPIX 131072
#define NWAVES 4096            // 1024 blocks * 4 waves
#define MSE_DENOM 8388608.0f   // NPIX*DIM
#define EPSF 1e-5f
#define CHUNK_BYTES 24576      // 3 splits * 64 codes * 64 dims * 2B
#define CHUNK_SHORTS 12288
#define NCHUNK 16              // chunks per codebook

__device__ __forceinline__ unsigned short f2bf(float x) {  // RNE fp32->bf16
    unsigned u = __float_as_uint(x);
    u += 0x7fffu + ((u >> 16) & 1u);
    return (unsigned short)(u >> 16);
}
__device__ __forceinline__ float bf2f(unsigned short h) {  // exact bf16->fp32
    return __uint_as_float(((unsigned)h) << 16);
}

// ------------- kernel 0: -0.5*||e||^2 per code (fp32, exact) -------------
__global__ __launch_bounds__(64) void rvq_norms(const float* __restrict__ cb,
                                                float* __restrict__ nrmh) {
    int code = blockIdx.x * 64 + threadIdx.x;  // 0..4095
    const float4* row = reinterpret_cast<const float4*>(cb + (size_t)code * DIM);
    float s0 = 0.f, s1 = 0.f, s2 = 0.f, s3 = 0.f;
#pragma unroll
    for (int k = 0; k < 16; ++k) {
        float4 v = row[k];
        s0 = fmaf(v.x, v.x, s0); s1 = fmaf(v.y, v.y, s1);
        s2 = fmaf(v.z, v.z, s2); s3 = fmaf(v.w, v.w, s3);
    }
    nrmh[code] = -0.5f * ((s0 + s1) + (s2 + s3));
}

// ------------- kernel 0b: pre-split codebook -> swizzled bf16x3 image ----
// R5-validated layout: [cb i][chunk c(64 codes)] 24KB blobs, 3 planes of
// 8192B, addr=(code*128+dg*32+h*16)^((code&7)<<4). Byte-identical to the
// main kernel's LDS chunk buffer. UNCHANGED from the validated R14 image.
__global__ __launch_bounds__(256) void rvq_presplit(const float* __restrict__ cb,
                                                    unsigned short* __restrict__ gB) {
    int blk = blockIdx.x;            // i*16 + c
    int tid = threadIdx.x;
    int code = tid >> 2, dg = tid & 3;
    int c0 = (blk & 15) << 6;
    int i  = blk >> 4;
    const float4* s4 = reinterpret_cast<const float4*>(
        cb + ((size_t)i * NE + c0 + code) * DIM + dg * 16);
    float v[16];
    {
        float4 q;
        q = s4[0]; v[0]=q.x; v[1]=q.y; v[2]=q.z; v[3]=q.w;
        q = s4[1]; v[4]=q.x; v[5]=q.y; v[6]=q.z; v[7]=q.w;
        q = s4[2]; v[8]=q.x; v[9]=q.y; v[10]=q.z; v[11]=q.w;
        q = s4[3]; v[12]=q.x; v[13]=q.y; v[14]=q.z; v[15]=q.w;
    }
    char* outc = reinterpret_cast<char*>(gB + (size_t)blk * CHUNK_SHORTS);
    int linbase = code * 128 + dg * 32;
    int sw = (code & 7) << 4;
#pragma unroll
    for (int h = 0; h < 2; ++h) {
        short8 p1, p2, p3;
#pragma unroll
        for (int e = 0; e < 8; ++e) {
            float t = v[h * 8 + e];
            unsigned short u1 = f2bf(t); t -= bf2f(u1);
            unsigned short u2 = f2bf(t); t -= bf2f(u2);
            unsigned short u3 = f2bf(t);
            p1[e] = (short)u1; p2[e] = (short)u2; p3[e] = (short)u3;
        }
        int a = (linbase + h * 16) ^ sw;
        *reinterpret_cast<short8*>(outc + a)         = p1;
        *reinterpret_cast<short8*>(outc + 8192 + a)  = p2;
        *reinterpret_cast<short8*>(outc + 16384 + a) = p3;
    }
}

// async 16B/lane global->LDS: wave-uniform LDS base, per-lane global src.
__device__ __forceinline__ void gload16(const void* gsrc, void* ldst) {
    __builtin_amdgcn_global_load_lds(
        (const __attribute__((address_space(1))) unsigned int*)gsrc,
        (__attribute__((address_space(3))) unsigned int*)ldst, 16, 0, 0);
}

// ------------- kernel 1: MFMA RVQ, M=32, 32x32x16 shape ------------------
// R14 pipeline (the 382us validated skeleton) with the MFMA shape changed
// 16x16x32 -> 32x32x16: 4064 vs 3377 FLOP/cyc on the matrix pipe (+20%,
// m119) and HALF the MFMA instructions (48 vs 96 per chunk; ds_read count
// unchanged at 24 b128). Wave = one 32-row A-tile (q=lane&31 -> pixel,
// h=lane>>5 -> k-half): A row=lane&31, k=h*8+e (same lane-mod-M pattern
// as the validated 16x16x32 operands); C/D col=lane&31 (code), row=
// (reg&3)+8*(reg>>2)+4*h (HW-verified m74/m101). Per 32-code block: 24
// chained MFMA (6 products x 4 K-blocks) into one f32x16 acc (chained
// accumulation hits peak, m119). Same image, same swizzle (read addr
// matches presplit byte map with dg=kb, hh=h). Accumulation order differs
// from R14 (~1ulp reorder, same class as validated R7/R15 reorders).
__global__ __launch_bounds__(256, 2) void rvq_main(
    const float* __restrict__ z, const unsigned short* __restrict__ gB,
    const float* __restrict__ nrmh, const float* __restrict__ cb,
    float* __restrict__ out_zq, float* __restrict__ out_idx,
    unsigned* __restrict__ hist, float* __restrict__ msePartial)
{
    __shared__ uint4 sB[2][CHUNK_BYTES / 16];   // 48 KB double buffer
    __shared__ int   sBest[4][32];

    const int tid  = threadIdx.x;
    const int lane = tid & 63;
    const int wid  = tid >> 6;
    const int q    = lane & 31;   // A-row (pixel) / D-col (code offset)
    const int h    = lane >> 5;   // k-half selector
    const int blockPix = blockIdx.x * 128;
    char* sBase = reinterpret_cast<char*>(sB);
    const int sw = (q & 7) << 4;  // code&7 == q&7 (block bases are mult of 32)

    // cb0 chunk0: issue before anything else (z-load+split covers latency)
#pragma unroll
    for (int k = 0; k < 6; ++k)
        gload16(reinterpret_cast<const char*>(gB) + k * 4096 + tid * 16,
                sBase + k * 4096 + tid * 16);

    const int pf = blockPix + wid * 32 + q;
    const size_t zb = (size_t)(pf >> 14) * 1048576 + (size_t)(pf & 16383);

    float r[4][8];   // [kb][e], dim = kb*16 + h*8 + e
#pragma unroll
    for (int kb = 0; kb < 4; ++kb)
#pragma unroll
        for (int e = 0; e < 8; ++e)
            r[kb][e] = z[zb + (size_t)(kb * 16 + h * 8 + e) * HW];

    for (int i = 0; i < NCB; ++i) {
        const char* gBi = reinterpret_cast<const char*>(gB) + (size_t)i * NCHUNK * CHUNK_BYTES;
        const float* nrm_i = nrmh + i * NE;

        // bf16x3 split of r -> A-frags (once per codebook)
        short8 A[3][4];
#pragma unroll
        for (int kb = 0; kb < 4; ++kb)
#pragma unroll
            for (int e = 0; e < 8; ++e) {
                float t = r[kb][e];
                unsigned short u1 = f2bf(t); t -= bf2f(u1);
                unsigned short u2 = f2bf(t); t -= bf2f(u2);
                unsigned short u3 = f2bf(t);
                A[0][kb][e] = (short)u1;
                A[1][kb][e] = (short)u2;
                A[2][kb][e] = (short)u3;
            }

        float maxv[16]; int maxi[16];
#pragma unroll
        for (int rr = 0; rr < 16; ++rr) { maxv[rr] = -3.4e38f; maxi[rr] = 0; }

        for (int c = 0; c < NCHUNK; ++c) {
            // drains own vmcnt + syncs: buf[c&1] populated for ALL waves;
            // buf[(c+1)&1]'s last readers (compute(c-1)) all done.
            __syncthreads();
            if (c < NCHUNK - 1) {   // issue next chunk into the freed buffer
                const char* gc = gBi + (size_t)(c + 1) * CHUNK_BYTES;
                char* sbn = sBase + ((c + 1) & 1) * CHUNK_BYTES;
#pragma unroll
                for (int k = 0; k < 6; ++k)
                    gload16(gc + k * 4096 + tid * 16, sbn + k * 4096 + tid * 16);
            }
            const char* sbc = sBase + (c & 1) * CHUNK_BYTES;

#pragma unroll
            for (int b = 0; b < 2; ++b) {     // two 32-code blocks per chunk
                const int code = (c << 6) + (b << 5) + q;
                float nh = nrm_i[code];
                f32x16 acc;
#pragma unroll
                for (int rr = 0; rr < 16; ++rr) acc[rr] = nh;

                __builtin_amdgcn_s_setprio(1);
#pragma unroll
                for (int sb = 0; sb < 3; ++sb) {
#pragma unroll
                    for (int kb = 0; kb < 4; ++kb) {
                        short8 Bf = *reinterpret_cast<const short8*>(
                            sbc + sb * 8192 +
                            (((b << 12) + (q << 7) + kb * 32 + h * 16) ^ sw));
#pragma unroll
                        for (int sa = 0; sa < 3 - sb; ++sa)   // products sa+sb<=2
                            acc = __builtin_amdgcn_mfma_f32_32x32x16_bf16(
                                A[sa][kb], Bf, acc, 0, 0, 0);
                    }
                }
                __builtin_amdgcn_s_setprio(0);

#pragma unroll
                for (int rr = 0; rr < 16; ++rr) {
                    float s = acc[rr];             // argmax s == argmin dist
                    if (s > maxv[rr]) { maxv[rr] = s; maxi[rr] = code; }
                }
            }
        }

        // next codebook's chunk0: issue NOW so the epilogue covers latency.
        if (i < NCB - 1) {
            const char* gn = reinterpret_cast<const char*>(gB)
                           + (size_t)(i + 1) * NCHUNK * CHUNK_BYTES;
#pragma unroll
            for (int k = 0; k < 6; ++k)
                gload16(gn + k * 4096 + tid * 16, sBase + k * 4096 + tid * 16);
        }

        // cross-lane argmax per reg over the 32-lane half, idx tie-break
#pragma unroll
        for (int rr = 0; rr < 16; ++rr) {
            float v = maxv[rr]; int ix = maxi[rr];
#pragma unroll
            for (int off = 1; off < 32; off <<= 1) {   // stays within half
                float ov = __shfl_xor(v, off, 64);
                int   oi = __shfl_xor(ix, off, 64);
                if (ov > v || (ov == v && oi < ix)) { v = ov; ix = oi; }
            }
            maxi[rr] = ix;
        }
        // wave-private exchange (same-wave LDS ordering; no barrier needed)
        if (q == 0) {   // lanes 0 and 32: each writes its half's 16 rows
#pragma unroll
            for (int rr = 0; rr < 16; ++rr) {
                int row = (rr & 3) + 8 * (rr >> 2) + 4 * h;
                sBest[wid][row] = maxi[rr];
            }
        }

        const float* cbi = cb + (size_t)i * NE * DIM;
        if (lane < 32) {  // idx output + histogram, one writer per row
            int pfr = blockPix + wid * 32 + lane;
            int bb = pfr >> 14, yy = (pfr >> 7) & 127, xx = pfr & 127;
            int bi = sBest[wid][lane];
            size_t off = (size_t)bb * 65536 + (size_t)(yy >> 2) * 2048
                       + (size_t)(xx >> 2) * 64
                       + (size_t)(((yy & 3) << 2) + (xx & 3)) * 4 + (size_t)i;
            out_idx[off] = (float)bi;
            atomicAdd(&hist[i * NE + bi], 1u);
        }

        // residual update from ORIGINAL fp32 codebook (keeps r exact)
        {
            const int best = sBest[wid][q];
            const float* er = cbi + (size_t)best * DIM + h * 8;
#pragma unroll
            for (int kb = 0; kb < 4; ++kb) {
                float4 q0 = *reinterpret_cast<const float4*>(er + kb * 16);
                float4 q1 = *reinterpret_cast<const float4*>(er + kb * 16 + 4);
                r[kb][0] -= q0.x; r[kb][1] -= q0.y;
                r[kb][2] -= q0.z; r[kb][3] -= q0.w;
                r[kb][4] -= q1.x; r[kb][5] -= q1.y;
                r[kb][6] -= q1.z; r[kb][7] -= q1.w;
            }
        }

        // MSE partial: (z_q - r_old)^2 = r_new^2 (each dim counted once)
        float s = 0.f;
#pragma unroll
        for (int kb = 0; kb < 4; ++kb)
#pragma unroll
            for (int e = 0; e < 8; ++e) s = fmaf(r[kb][e], r[kb][e], s);
#pragma unroll
        for (int d_ = 32; d_ > 0; d_ >>= 1) s += __shfl_down(s, d_, 64);
        if (lane == 0) msePartial[i * NWAVES + blockIdx.x * 4 + wid] = s;
    }

    // epilogue: z_q = z - r_final (telescoped straight-through sum)
#pragma unroll
    for (int kb = 0; kb < 4; ++kb)
#pragma unroll
        for (int e = 0; e < 8; ++e) {
            size_t o = zb + (size_t)(kb * 16 + h * 8 + e) * HW;
            out_zq[o] = z[o] - r[kb][e];
        }
}

// ---------------- kernel 2: deterministic loss finalize ----------------
__global__ __launch_bounds__(1024) void rvq_finalize(
    const unsigned* __restrict__ hist, const float* __restrict__ msePartial,
    float* __restrict__ out_loss)
{
    __shared__ float red[1024];
    int t = threadIdx.x;
    float loss = 0.f;
    for (int i = 0; i < NCB; ++i) {
        float cnt = (float)hist[i * NE + t];
        float prob = (cnt + EPSF) / (131072.0f + EPSF * 1024.0f);
        red[t] = -prob * logf(prob + EPSF);
        __syncthreads();
        for (int s = 512; s > 0; s >>= 1) { if (t < s) red[t] += red[t + s]; __syncthreads(); }
        float entropy = red[0];
        __syncthreads();
        float acc = 0.f;
#pragma unroll
        for (int k = 0; k < 4; ++k) acc += msePartial[i * NWAVES + k * 1024 + t];
        red[t] = acc;
        __syncthreads();
        for (int s = 512; s > 0; s >>= 1) { if (t < s) red[t] += red[t + s]; __syncthreads(); }
        float mse_sum = red[0];
        __syncthreads();
        loss += 0.25f * (mse_sum / MSE_DENOM) + 0.01f * (logf(1024.0f) - entropy);
    }
    if (t == 0) out_loss[0] = loss;
}

extern "C" void kernel_launch(void* const* d_in, const int* in_sizes, int n_in,
                              void* d_out, int out_size, void* d_ws, size_t ws_size,
                              hipStream_t stream) {
    const float* z  = (const float*)d_in[0];
    const float* cb = (const float*)d_in[1];

    float* out      = (float*)d_out;
    float* out_zq   = out;                    // 8388608
    float* out_loss = out + 8388608;          // 1
    float* out_idx  = out + 8388609;          // 524288 (indices as float)

    unsigned* hist        = (unsigned*)d_ws;                         // 16 KB
    float*    nrmh        = (float*)((char*)d_ws + 16384);           // 16 KB
    float*    msePartial  = (float*)((char*)d_ws + 32768);           // 64 KB (4*4096 f32)
    unsigned short* gB    = (unsigned short*)((char*)d_ws + 163840); // 1.5 MB pre-split image

    hipMemsetAsync(d_ws, 0, 16384, stream);   // zero histogram (deterministic)
    rvq_norms<<<64, 64, 0, stream>>>(cb, nrmh);
    rvq_presplit<<<64, 256, 0, stream>>>(cb, gB);
    rvq_main<<<1024, 256, 0, stream>>>(z, gB, nrmh, cb, out_zq, out_idx, hist, msePartial);
    rvq_finalize<<<1, 1024, 0, stream>>>(hist, msePartial, out_loss);
}

// Round 24
// 382.257 us; speedup vs baseline: 1.1115x; 1.1115x over previous
//
#include <hip/hip_runtime.h>
#include <math.h>

typedef __attribute__((ext_vector_type(8))) short short8;
typedef __attribute__((ext_vector_type(4))) float f32x4;

#define NCB 4
#define NE 1024
#define DIM 64
#define HW 16384
#define NPIX 131072
#define NWAVES 4096            // 1024 blocks * 4 waves
#define MSE_DENOM 8388608.0f   // NPIX*DIM
#define EPSF 1e-5f
#define CHUNK_BYTES 24576      // 3 splits * 64 codes * 64 dims * 2B
#define CHUNK_SHORTS 12288
#define NCHUNK 16              // chunks per codebook

__device__ __forceinline__ unsigned short f2bf(float x) {  // RNE fp32->bf16
    unsigned u = __float_as_uint(x);
    u += 0x7fffu + ((u >> 16) & 1u);
    return (unsigned short)(u >> 16);
}
__device__ __forceinline__ float bf2f(unsigned short h) {  // exact bf16->fp32
    return __uint_as_float(((unsigned)h) << 16);
}

// ------------- kernel 0: -0.5*||e||^2 per code (fp32, exact) -------------
__global__ __launch_bounds__(64) void rvq_norms(const float* __restrict__ cb,
                                                float* __restrict__ nrmh) {
    int code = blockIdx.x * 64 + threadIdx.x;  // 0..4095
    const float4* row = reinterpret_cast<const float4*>(cb + (size_t)code * DIM);
    float s0 = 0.f, s1 = 0.f, s2 = 0.f, s3 = 0.f;
#pragma unroll
    for (int k = 0; k < 16; ++k) {
        float4 v = row[k];
        s0 = fmaf(v.x, v.x, s0); s1 = fmaf(v.y, v.y, s1);
        s2 = fmaf(v.z, v.z, s2); s3 = fmaf(v.w, v.w, s3);
    }
    nrmh[code] = -0.5f * ((s0 + s1) + (s2 + s3));
}

// ------------- kernel 0b: pre-split codebook -> swizzled bf16x3 image ----
// R5-validated layout: [cb i][chunk c(64 codes)] 24KB blobs, 3 planes of
// 8192B, addr=(code*128+dg*32+h*16)^((code&7)<<4). Byte-identical to the
// main kernel's LDS chunk buffer.
__global__ __launch_bounds__(256) void rvq_presplit(const float* __restrict__ cb,
                                                    unsigned short* __restrict__ gB) {
    int blk = blockIdx.x;            // i*16 + c
    int tid = threadIdx.x;
    int code = tid >> 2, dg = tid & 3;
    int c0 = (blk & 15) << 6;
    int i  = blk >> 4;
    const float4* s4 = reinterpret_cast<const float4*>(
        cb + ((size_t)i * NE + c0 + code) * DIM + dg * 16);
    float v[16];
    {
        float4 q;
        q = s4[0]; v[0]=q.x; v[1]=q.y; v[2]=q.z; v[3]=q.w;
        q = s4[1]; v[4]=q.x; v[5]=q.y; v[6]=q.z; v[7]=q.w;
        q = s4[2]; v[8]=q.x; v[9]=q.y; v[10]=q.z; v[11]=q.w;
        q = s4[3]; v[12]=q.x; v[13]=q.y; v[14]=q.z; v[15]=q.w;
    }
    char* outc = reinterpret_cast<char*>(gB + (size_t)blk * CHUNK_SHORTS);
    int linbase = code * 128 + dg * 32;
    int sw = (code & 7) << 4;
#pragma unroll
    for (int h = 0; h < 2; ++h) {
        short8 p1, p2, p3;
#pragma unroll
        for (int e = 0; e < 8; ++e) {
            float t = v[h * 8 + e];
            unsigned short u1 = f2bf(t); t -= bf2f(u1);
            unsigned short u2 = f2bf(t); t -= bf2f(u2);
            unsigned short u3 = f2bf(t);
            p1[e] = (short)u1; p2[e] = (short)u2; p3[e] = (short)u3;
        }
        int a = (linbase + h * 16) ^ sw;
        *reinterpret_cast<short8*>(outc + a)         = p1;
        *reinterpret_cast<short8*>(outc + 8192 + a)  = p2;
        *reinterpret_cast<short8*>(outc + 16384 + a) = p3;
    }
}

// async 16B/lane global->LDS: wave-uniform LDS base, per-lane global src.
__device__ __forceinline__ void gload16(const void* gsrc, void* ldst) {
    __builtin_amdgcn_global_load_lds(
        (const __attribute__((address_space(1))) unsigned int*)gsrc,
        (__attribute__((address_space(3))) unsigned int*)ldst, 16, 0, 0);
}

// ------------- kernel 1: MFMA RVQ, M=32, double-buffer (FINAL: R14) ------
// 1024 blocks x 4 waves, (256,2). The validated 382us kernel — best of
// eleven structural variants (counted vmcnt, buffer depth, chunk size,
// barrier-free per-wave staging, B-prefetch, 6-chain ILP, two candidate-
// filter algorithms, 32x32x16 shape), all of which landed in [382,502]us.
// The plateau is the intersection of the register-bracket wall (M=32
// state spills below the 256-reg bracket -> 2 waves/SIMD) and the serial
// per-wave skeleton (VALU scan + staging drains can't hide behind 2
// lockstep waves). Per chunk: __syncthreads (drains own vmcnt -> all
// waves' gloads(c) landed; compute(c-1) done = write target free); issue
// gloads(c+1); compute (4 subs x [6 ds_read_b128 + 24 MFMA, K-halves
// chained into 2 acc chains]). s = r.e - 0.5||e||^2 in-MFMA; argmax s ==
// argmin dist; strict-> scan + idx tie-break = jnp.argmin semantics.
__global__ __launch_bounds__(256, 2) void rvq_main(
    const float* __restrict__ z, const unsigned short* __restrict__ gB,
    const float* __restrict__ nrmh, const float* __restrict__ cb,
    float* __restrict__ out_zq, float* __restrict__ out_idx,
    unsigned* __restrict__ hist, float* __restrict__ msePartial)
{
    __shared__ uint4 sB[2][CHUNK_BYTES / 16];   // 48 KB double buffer
    __shared__ int   sBest[4][32];

    const int tid  = threadIdx.x;
    const int lane = tid & 63;
    const int wid  = tid >> 6;
    const int col  = lane & 15;   // A-row within tile / D-col (code)
    const int g    = lane >> 4;   // k-group (8 dims) / D row-group
    const int blockPix = blockIdx.x * 128;
    char* sBase = reinterpret_cast<char*>(sB);
    const int sw = (col & 7) << 4;

    // cb0 chunk0: issue before anything else (z-load+split covers latency)
#pragma unroll
    for (int k = 0; k < 6; ++k)
        gload16(reinterpret_cast<const char*>(gB) + k * 4096 + tid * 16,
                sBase + k * 4096 + tid * 16);

    size_t zb[2];
#pragma unroll
    for (int m = 0; m < 2; ++m) {
        int pf = blockPix + wid * 32 + m * 16 + col;
        zb[m] = (size_t)(pf >> 14) * 1048576 + (size_t)(pf & 16383);
    }

    float r[2][2][8];   // [m][kh][e], dim = kh*32 + g*8 + e
#pragma unroll
    for (int m = 0; m < 2; ++m)
#pragma unroll
        for (int kh = 0; kh < 2; ++kh)
#pragma unroll
            for (int e = 0; e < 8; ++e)
                r[m][kh][e] = z[zb[m] + (size_t)(kh * 32 + g * 8 + e) * HW];

    for (int i = 0; i < NCB; ++i) {
        const char* gBi = reinterpret_cast<const char*>(gB) + (size_t)i * NCHUNK * CHUNK_BYTES;
        const float* nrm_i = nrmh + i * NE;

        // bf16x3 split of r -> A-frags (once per codebook)
        short8 A[3][2][2];
#pragma unroll
        for (int m = 0; m < 2; ++m)
#pragma unroll
            for (int kh = 0; kh < 2; ++kh)
#pragma unroll
                for (int e = 0; e < 8; ++e) {
                    float t = r[m][kh][e];
                    unsigned short u1 = f2bf(t); t -= bf2f(u1);
                    unsigned short u2 = f2bf(t); t -= bf2f(u2);
                    unsigned short u3 = f2bf(t);
                    A[0][m][kh][e] = (short)u1;
                    A[1][m][kh][e] = (short)u2;
                    A[2][m][kh][e] = (short)u3;
                }

        float maxv[2][4]; int maxi[2][4];
#pragma unroll
        for (int m = 0; m < 2; ++m)
#pragma unroll
            for (int rr = 0; rr < 4; ++rr) { maxv[m][rr] = -3.4e38f; maxi[m][rr] = 0; }

        for (int c = 0; c < NCHUNK; ++c) {
            // drains own vmcnt (gloads(c) covered by compute(c-1)) + syncs:
            // after this, buf[c&1] is fully populated for ALL waves, and
            // buf[(c+1)&1]'s last readers (compute(c-1)) are all done.
            __syncthreads();
            if (c < NCHUNK - 1) {   // issue next chunk into the freed buffer
                const char* gc = gBi + (size_t)(c + 1) * CHUNK_BYTES;
                char* sbn = sBase + ((c + 1) & 1) * CHUNK_BYTES;
#pragma unroll
                for (int k = 0; k < 6; ++k)
                    gload16(gc + k * 4096 + tid * 16, sbn + k * 4096 + tid * 16);
            }
            const char* sbc = sBase + (c & 1) * CHUNK_BYTES;

#pragma unroll
            for (int sub = 0; sub < 4; ++sub) {
                const int code = (sub << 4) + col;
                float nh = nrm_i[(c << 6) + code];
                f32x4 acc[2];
#pragma unroll
                for (int rr = 0; rr < 4; ++rr) { acc[0][rr] = nh; acc[1][rr] = nh; }

                __builtin_amdgcn_s_setprio(1);
#pragma unroll
                for (int sb = 0; sb < 3; ++sb) {   // B-split-major: 2 B regs live
                    short8 B0 = *reinterpret_cast<const short8*>(
                        sbc + sb * 8192 + ((((code << 7) + (g << 4))) ^ sw));
                    short8 B1 = *reinterpret_cast<const short8*>(
                        sbc + sb * 8192 + ((((code << 7) + 64 + (g << 4))) ^ sw));
#pragma unroll
                    for (int sa = 0; sa < 3 - sb; ++sa) {   // products with sa+sb<=2
                        acc[0] = __builtin_amdgcn_mfma_f32_16x16x32_bf16(A[sa][0][0], B0, acc[0], 0, 0, 0);
                        acc[1] = __builtin_amdgcn_mfma_f32_16x16x32_bf16(A[sa][1][0], B0, acc[1], 0, 0, 0);
                        acc[0] = __builtin_amdgcn_mfma_f32_16x16x32_bf16(A[sa][0][1], B1, acc[0], 0, 0, 0);
                        acc[1] = __builtin_amdgcn_mfma_f32_16x16x32_bf16(A[sa][1][1], B1, acc[1], 0, 0, 0);
                    }
                }
                __builtin_amdgcn_s_setprio(0);

#pragma unroll
                for (int m = 0; m < 2; ++m)
#pragma unroll
                    for (int rr = 0; rr < 4; ++rr) {
                        float s = acc[m][rr];      // argmax s == argmin dist
                        if (s > maxv[m][rr]) { maxv[m][rr] = s; maxi[m][rr] = (c << 6) + code; }
                    }
            }
        }

        // next codebook's chunk0: issue NOW so the epilogue covers latency.
        // buf0's last readers were compute(14) — all waves passed the c=15
        // barrier, so they're done.
        if (i < NCB - 1) {
            const char* gn = reinterpret_cast<const char*>(gB)
                           + (size_t)(i + 1) * NCHUNK * CHUNK_BYTES;
#pragma unroll
            for (int k = 0; k < 6; ++k)
                gload16(gn + k * 4096 + tid * 16, sBase + k * 4096 + tid * 16);
        }

        // cross-lane argmax within each 16-lane group, idx tie-break
#pragma unroll
        for (int m = 0; m < 2; ++m)
#pragma unroll
            for (int rr = 0; rr < 4; ++rr) {
                float v = maxv[m][rr]; int ix = maxi[m][rr];
#pragma unroll
                for (int off = 1; off < 16; off <<= 1) {
                    float ov = __shfl_xor(v, off, 64);
                    int   oi = __shfl_xor(ix, off, 64);
                    if (ov > v || (ov == v && oi < ix)) { v = ov; ix = oi; }
                }
                maxi[m][rr] = ix;
            }
        // wave-private exchange (same-wave LDS ordering; no barrier needed)
        if (col == 0) {
#pragma unroll
            for (int m = 0; m < 2; ++m)
#pragma unroll
                for (int rr = 0; rr < 4; ++rr)
                    sBest[wid][m * 16 + g * 4 + rr] = maxi[m][rr];
        }

        const float* cbi = cb + (size_t)i * NE * DIM;
        if (lane < 16) {  // idx output + histogram, one writer per row
#pragma unroll
            for (int m = 0; m < 2; ++m) {
                int pfr = blockPix + wid * 32 + m * 16 + lane;
                int bb = pfr >> 14, yy = (pfr >> 7) & 127, xx = pfr & 127;
                int bi = sBest[wid][m * 16 + lane];
                size_t off = (size_t)bb * 65536 + (size_t)(yy >> 2) * 2048
                           + (size_t)(xx >> 2) * 64
                           + (size_t)(((yy & 3) << 2) + (xx & 3)) * 4 + (size_t)i;
                out_idx[off] = (float)bi;
                atomicAdd(&hist[i * NE + bi], 1u);
            }
        }

        // residual update from ORIGINAL fp32 codebook (keeps r exact)
#pragma unroll
        for (int m = 0; m < 2; ++m) {
            const int best = sBest[wid][m * 16 + col];
            const float* er = cbi + (size_t)best * DIM;
#pragma unroll
            for (int kh = 0; kh < 2; ++kh) {
                const float4* e4 = reinterpret_cast<const float4*>(er + kh * 32 + g * 8);
                float4 q0 = e4[0], q1 = e4[1];
                r[m][kh][0] -= q0.x; r[m][kh][1] -= q0.y;
                r[m][kh][2] -= q0.z; r[m][kh][3] -= q0.w;
                r[m][kh][4] -= q1.x; r[m][kh][5] -= q1.y;
                r[m][kh][6] -= q1.z; r[m][kh][7] -= q1.w;
            }
        }

        // MSE partial: (z_q - r_old)^2 = r_new^2
        float s = 0.f;
#pragma unroll
        for (int m = 0; m < 2; ++m)
#pragma unroll
            for (int kh = 0; kh < 2; ++kh)
#pragma unroll
                for (int e = 0; e < 8; ++e) s = fmaf(r[m][kh][e], r[m][kh][e], s);
#pragma unroll
        for (int d_ = 32; d_ > 0; d_ >>= 1) s += __shfl_down(s, d_, 64);
        if (lane == 0) msePartial[i * NWAVES + blockIdx.x * 4 + wid] = s;
    }

    // epilogue: z_q = z - r_final (telescoped straight-through sum)
#pragma unroll
    for (int m = 0; m < 2; ++m)
#pragma unroll
        for (int kh = 0; kh < 2; ++kh)
#pragma unroll
            for (int e = 0; e < 8; ++e) {
                size_t o = zb[m] + (size_t)(kh * 32 + g * 8 + e) * HW;
                out_zq[o] = z[o] - r[m][kh][e];
            }
}

// ---------------- kernel 2: deterministic loss finalize ----------------
__global__ __launch_bounds__(1024) void rvq_finalize(
    const unsigned* __restrict__ hist, const float* __restrict__ msePartial,
    float* __restrict__ out_loss)
{
    __shared__ float red[1024];
    int t = threadIdx.x;
    float loss = 0.f;
    for (int i = 0; i < NCB; ++i) {
        float cnt = (float)hist[i * NE + t];
        float prob = (cnt + EPSF) / (131072.0f + EPSF * 1024.0f);
        red[t] = -prob * logf(prob + EPSF);
        __syncthreads();
        for (int s = 512; s > 0; s >>= 1) { if (t < s) red[t] += red[t + s]; __syncthreads(); }
        float entropy = red[0];
        __syncthreads();
        float acc = 0.f;
#pragma unroll
        for (int k = 0; k < 4; ++k) acc += msePartial[i * NWAVES + k * 1024 + t];
        red[t] = acc;
        __syncthreads();
        for (int s = 512; s > 0; s >>= 1) { if (t < s) red[t] += red[t + s]; __syncthreads(); }
        float mse_sum = red[0];
        __syncthreads();
        loss += 0.25f * (mse_sum / MSE_DENOM) + 0.01f * (logf(1024.0f) - entropy);
    }
    if (t == 0) out_loss[0] = loss;
}

extern "C" void kernel_launch(void* const* d_in, const int* in_sizes, int n_in,
                              void* d_out, int out_size, void* d_ws, size_t ws_size,
                              hipStream_t stream) {
    const float* z  = (const float*)d_in[0];
    const float* cb = (const float*)d_in[1];

    float* out      = (float*)d_out;
    float* out_zq   = out;                    // 8388608
    float* out_loss = out + 8388608;          // 1
    float* out_idx  = out + 8388609;          // 524288 (indices as float)

    unsigned* hist        = (unsigned*)d_ws;                         // 16 KB
    float*    nrmh        = (float*)((char*)d_ws + 16384);           // 16 KB
    float*    msePartial  = (float*)((char*)d_ws + 32768);           // 64 KB (4*4096 f32)
    unsigned short* gB    = (unsigned short*)((char*)d_ws + 163840); // 1.5 MB pre-split image

    hipMemsetAsync(d_ws, 0, 16384, stream);   // zero histogram (deterministic)
    rvq_norms<<<64, 64, 0, stream>>>(cb, nrmh);
    rvq_presplit<<<64, 256, 0, stream>>>(cb, gB);
    rvq_main<<<1024, 256, 0, stream>>>(z, gB, nrmh, cb, out_zq, out_idx, hist, msePartial);
    rvq_finalize<<<1, 1024, 0, stream>>>(hist, msePartial, out_loss);
}